// Round 15
// baseline (132.789 us; speedup 1.0000x reference)
//
#include <hip/hip_runtime.h>

#define BB 64
#define SS 2048
#define HH 512
#define MROWS (BB*SS)  // 131072

typedef __attribute__((ext_vector_type(8))) short short8;
typedef __attribute__((ext_vector_type(4))) float f32x4;

__device__ inline unsigned short f2bf(float f){
  unsigned int u = __float_as_uint(f);
  u += 0x7FFFu + ((u >> 16) & 1u);   // RNE
  return (unsigned short)(u >> 16);
}
__device__ inline float bf2f(unsigned short u){
  return __uint_as_float((unsigned int)u << 16);
}

// batch_lens may be int64 (reference) or int32. For int64 LE the high word of
// element 0 is 0 (lens in [1,2048]); for int32, p[1] is a len >= 1.
__device__ inline int read_len(const void* lens, int i){
  const int* p = (const int*)lens;
  if (p[1] == 0) return (int)((const long long*)lens)[i];
  return p[i];
}

__device__ inline float fast_tanh(float x){
  x = fminf(fmaxf(x, -15.f), 15.f);
  float e = __expf(2.f * x);
  return (e - 1.f) / (e + 1.f);
}

__device__ inline void gload16(const void* gptr, void* lptr){
  __builtin_amdgcn_global_load_lds(
      (const __attribute__((address_space(1))) void*)gptr,
      (__attribute__((address_space(3))) void*)lptr, 16, 0, 0);
}

__device__ inline short8 cvt8p(float4 x0, float4 x1){
  short8 r;
  r[0] = (short)f2bf(x0.x); r[1] = (short)f2bf(x0.y);
  r[2] = (short)f2bf(x0.z); r[3] = (short)f2bf(x0.w);
  r[4] = (short)f2bf(x1.x); r[5] = (short)f2bf(x1.y);
  r[6] = (short)f2bf(x1.z); r[7] = (short)f2bf(x1.w);
  return r;
}

// ---------- tiny pre-convert: W only (1 MB -> 512 KB bf16) ----------
__global__ __launch_bounds__(256) void convw_kernel(
    const float* __restrict__ W, unsigned short* __restrict__ Wb)
{
  size_t base = (size_t)blockIdx.x * 64 * HH;
  int t = threadIdx.x;
  #pragma unroll
  for (int j = 0; j < 32; j++) {
    size_t idx = base + (size_t)j * 1024 + t * 4;
    float4 v = *(const float4*)(W + idx);
    unsigned int p0 = (unsigned int)f2bf(v.x) | ((unsigned int)f2bf(v.y) << 16);
    unsigned int p1 = (unsigned int)f2bf(v.z) | ((unsigned int)f2bf(v.w) << 16);
    *(uint2*)(Wb + idx) = make_uint2(p0, p1);
  }
}

// A LDS layout: [16 K-slices][128 rows][4 groups of 8 bf16], XOR-swizzled
// within each slice: phys_group = logical_group ^ (row & 3).
#define AS_IDX(SL, ROW, PG) ((SL) * 4096 + (ROW) * 32 + (PG) * 8)

// ---------- fused: A staged ONCE in LDS + 16-step GEMM + softmax + LDS-PV ----------
// BM=128, BN=512, BK=32, 512 thr / 8 waves as 2M x 4N, wave tile 64x128.
// As = full 128x512 bf16 tile (128 KB, written once in prologue).
// Bs = single-buffered 512x32 slice (32 KB). LDS = 160 KB exactly.
// PV reads A from LDS -> no global X re-read.
__global__ __launch_bounds__(512, 2) void scores_fused(
    const float* __restrict__ X, const unsigned short* __restrict__ Wb,
    const void* __restrict__ lens, const float* __restrict__ ctx,
    const float* __restrict__ pb, float* __restrict__ P,
    float* __restrict__ pm, float* __restrict__ ps)
{
  int bid = blockIdx.x;
  int mtile = (bid & 7) * 128 + (bid >> 3);   // XCD swizzle (1024 % 8 == 0)
  int s_start = (mtile * 128) & (SS - 1);
  int b = (mtile * 128) >> 11;
  int len = read_len(lens, b);
  if (s_start >= len) return;
  int cnt = min(128, len - s_start);

  __shared__ __align__(16) unsigned short As[16 * 4096];   // 128 KB
  __shared__ __align__(16) unsigned short Bs[512 * 32];    // 32 KB

  int tid = threadIdx.x;
  int lane = tid & 63;
  int w = tid >> 6;
  int wm = w >> 2, wn = w & 3; // 2M x 4N, wave tile 64 x 128
  int l15 = lane & 15, g = lane >> 4;   // g in 0..3

  // ---- prologue: stage the WHOLE A tile (fp32 -> bf16) once ----
  // thread t: row = t>>2, logical group lg = t&3 (8 cols), all 16 slices.
  {
    int arow = tid >> 2;
    int alg  = tid & 3;
    int apg  = alg ^ (arow & 3);
    const float* Ag = X + (size_t)(mtile * 128 + arow) * HH + alg * 8;
    #pragma unroll
    for (int s = 0; s < 16; s++) {
      float4 x0 = *(const float4*)(Ag + s * 32);
      float4 x1 = *(const float4*)(Ag + s * 32 + 4);
      *(short8*)&As[AS_IDX(s, arow, apg)] = cvt8p(x0, x1);
    }
  }

  f32x4 acc[4][8];
  #pragma unroll
  for (int i = 0; i < 4; i++)
    #pragma unroll
    for (int j = 0; j < 8; j++) acc[i][j] = (f32x4)0.f;

  // ---- B staging geometry: wave w covers rows [w*64, w*64+64), 4 instrs of
  // 16 rows x 4 groups each; linear LDS dest, inverse-swizzled source. ----
  int brow_i = lane >> 2;               // 0..15 row within instr
  int bpg    = lane & 3;                // phys group
  int cur_row_lo = w * 64;

  for (int t = 0; t < 16; ++t) {
    // stage B slice t (cols t*32 .. t*32+32)
    #pragma unroll
    for (int i_ = 0; i_ < 4; i_++) {
      int base = cur_row_lo + i_ * 16;
      int row = base + brow_i;
      int blg = bpg ^ (row & 3);
      gload16(Wb + (size_t)row * HH + t * 32 + blg * 8, &Bs[base * 32]);
    }
    __syncthreads();                    // B slice ready (+ prologue A at t=0)
    short8 af[4];
    #pragma unroll
    for (int im = 0; im < 4; im++) {
      int r = wm * 64 + im * 16 + l15;
      af[im] = *(const short8*)&As[AS_IDX(t, r, g ^ (r & 3))];
    }
    #pragma unroll
    for (int in = 0; in < 8; in++) {
      int r2 = wn * 128 + in * 16 + l15;
      short8 bq = *(const short8*)&Bs[r2 * 32 + ((g ^ (r2 & 3))) * 8];
      #pragma unroll
      for (int im = 0; im < 4; im++)
        acc[im][in] = __builtin_amdgcn_mfma_f32_16x16x32_bf16(
            af[im], bq, acc[im][in], 0, 0, 0);
    }
    __syncthreads();                    // Bs reads done before next overwrite
  }

  // ---- epilogue 1: tanh(P+pb)*ctx -> per-row score (scratch in Bs!) ----
  float pbv[8], ctxv[8];
  #pragma unroll
  for (int in = 0; in < 8; in++) {
    int a_g = wn * 128 + in * 16 + l15;
    pbv[in] = pb[a_g];
    ctxv[in] = ctx[a_g];
  }
  float* fb   = (float*)Bs;       // 32 KB scratch; As stays intact for PV
  float* red  = fb;               // [512]
  float* esh  = fb + 512;         // [128] unnormalized exp weights
  float* wrd  = fb + 640;         // [2] max
  float* wrd2 = fb + 642;         // [2] sum
  float* redq = fb + 1024;        // [8*64*8] = 16 KB PV reduce buffer
  #pragma unroll
  for (int im = 0; im < 4; im++) {
    #pragma unroll
    for (int r = 0; r < 4; r++) {
      float rowsum = 0.f;
      #pragma unroll
      for (int in = 0; in < 8; in++)
        rowsum += fast_tanh(acc[im][in][r] + pbv[in]) * ctxv[in];
      #pragma unroll
      for (int m = 1; m < 16; m <<= 1)
        rowsum += __shfl_xor(rowsum, m, 64);
      if (l15 == 0)
        red[wn * 128 + wm * 64 + im * 16 + g * 4 + r] = rowsum;
    }
  }
  __syncthreads();

  // ---- epilogue 2: block softmax partials (r7/r13-verified pattern) ----
  float sc = 0.f;
  if (tid < 128)
    sc = red[tid] + red[128 + tid] + red[256 + tid] + red[384 + tid];
  float v = (tid < 128 && tid < cnt) ? sc : -1e30f;
  #pragma unroll
  for (int off = 1; off < 64; off <<= 1) v = fmaxf(v, __shfl_xor(v, off, 64));
  if (tid < 128 && (tid & 63) == 0) wrd[tid >> 6] = v;
  __syncthreads();
  float m_loc = fmaxf(wrd[0], wrd[1]);
  float e = 0.f;
  if (tid < 128) {
    e = (tid < cnt) ? __expf(sc - m_loc) : 0.f;
    esh[tid] = e;
  }
  float s1 = e;
  #pragma unroll
  for (int off = 1; off < 64; off <<= 1) s1 += __shfl_xor(s1, off, 64);
  if (tid < 128 && (tid & 63) == 0) wrd2[tid >> 6] = s1;
  __syncthreads();   // esh + wrd2 visible
  if (tid == 0) {
    pm[mtile] = m_loc;
    ps[mtile] = wrd2[0] + wrd2[1];
  }

  // ---- epilogue 3: PV from the A tile in LDS (zero global reads) ----
  // thread = (col-octet oct 0..63, s-group sg 0..7); octet = 8 cols.
  int oct = tid & 63;
  int sg  = tid >> 6;
  int slice = oct >> 2;
  int lg2 = oct & 3;
  float a8[8];
  #pragma unroll
  for (int q = 0; q < 8; q++) a8[q] = 0.f;
  #pragma unroll
  for (int j = 0; j < 16; j++) {
    int s = sg + j * 8;
    float wv = esh[s];
    short8 xv = *(const short8*)&As[AS_IDX(slice, s, lg2 ^ (s & 3))];
    #pragma unroll
    for (int q = 0; q < 8; q++)
      a8[q] += wv * bf2f((unsigned short)xv[q]);
  }
  #pragma unroll
  for (int q = 0; q < 8; q++) redq[(size_t)sg * 512 + oct * 8 + q] = a8[q];
  __syncthreads();
  if (sg == 0) {   // tid 0..63
    #pragma unroll
    for (int q = 0; q < 8; q++) {
      float s4 = 0.f;
      #pragma unroll
      for (int k = 0; k < 8; k++) s4 += redq[(size_t)k * 512 + oct * 8 + q];
      a8[q] = s4;
    }
    f32x4 o0, o1;
    o0[0] = a8[0]; o0[1] = a8[1]; o0[2] = a8[2]; o0[3] = a8[3];
    o1[0] = a8[4]; o1[1] = a8[5]; o1[2] = a8[6]; o1[3] = a8[7];
    *(f32x4*)&P[(size_t)mtile * HH + oct * 8]     = o0;
    *(f32x4*)&P[(size_t)mtile * HH + oct * 8 + 4] = o1;
  }
}

// ---------- combine: rescale 16 block-partials per batch (r7-verified) ----------
__global__ __launch_bounds__(512) void combine_kernel(
    const float* __restrict__ P, const float* __restrict__ pm,
    const float* __restrict__ ps, const void* __restrict__ lens,
    float* __restrict__ out)
{
  int b = blockIdx.x;
  int tid = threadIdx.x;
  int len = read_len(lens, b);
  int nblk = (len + 127) >> 7;
  float m = -1e30f;
  for (int k = 0; k < nblk; ++k) m = fmaxf(m, pm[b * 16 + k]);
  float S = 0.f, acc = 0.f;
  for (int k = 0; k < nblk; ++k) {
    float f = __expf(pm[b * 16 + k] - m);
    S += f * ps[b * 16 + k];
    acc += f * P[(size_t)(b * 16 + k) * HH + tid];
  }
  out[(size_t)b * HH + tid] = acc / S;
}

// ================= fallback path (ws too small) =================
__global__ __launch_bounds__(256) void scores_fb(
    const float* __restrict__ X, const void* __restrict__ lens,
    const float* __restrict__ ctx, const float* __restrict__ W,
    const float* __restrict__ pb, float* __restrict__ sp)
{
  int bid = blockIdx.x;
  int wg = (bid & 7) * 512 + (bid >> 3);
  int ntile = wg & 3;
  int mtile = wg >> 2;
  int s_start = (mtile * 128) & (SS - 1);
  int b = (mtile * 128) >> 11;
  if (s_start >= read_len(lens, b)) return;

  __shared__ unsigned short As[128 * 72];
  __shared__ unsigned short Bs[128 * 72];

  int tid = threadIdx.x;
  int lane = tid & 63;
  int w = tid >> 6;
  int wm = w >> 1, wn = w & 1;
  int l15 = lane & 15, g = lane >> 4;

  f32x4 acc[4][4];
  #pragma unroll
  for (int i = 0; i < 4; i++)
    #pragma unroll
    for (int j = 0; j < 4; j++) acc[i][j] = (f32x4)0.f;

  int srow = tid >> 4;
  int scol = (tid & 15) * 4;
  const float* Xbase = X + (size_t)(mtile * 128) * HH;
  const float* Wbase = W + (size_t)(ntile * 128) * HH;

  for (int kt = 0; kt < HH; kt += 64) {
    #pragma unroll
    for (int i = 0; i < 8; i++) {
      int row = srow + i * 16;
      float4 va = *(const float4*)(Xbase + (size_t)row * HH + kt + scol);
      unsigned int p0 = (unsigned int)f2bf(va.x) | ((unsigned int)f2bf(va.y) << 16);
      unsigned int p1 = (unsigned int)f2bf(va.z) | ((unsigned int)f2bf(va.w) << 16);
      *(uint2*)&As[row * 72 + scol] = make_uint2(p0, p1);
      float4 vb = *(const float4*)(Wbase + (size_t)row * HH + kt + scol);
      unsigned int q0 = (unsigned int)f2bf(vb.x) | ((unsigned int)f2bf(vb.y) << 16);
      unsigned int q1 = (unsigned int)f2bf(vb.z) | ((unsigned int)f2bf(vb.w) << 16);
      *(uint2*)&Bs[row * 72 + scol] = make_uint2(q0, q1);
    }
    __syncthreads();
    #pragma unroll
    for (int kk = 0; kk < 64; kk += 32) {
      short8 af[4], bfr[4];
      int ko = kk + g * 8;
      #pragma unroll
      for (int im = 0; im < 4; im++)
        af[im] = *(const short8*)&As[(wm * 64 + im * 16 + l15) * 72 + ko];
      #pragma unroll
      for (int in = 0; in < 4; in++)
        bfr[in] = *(const short8*)&Bs[(wn * 64 + in * 16 + l15) * 72 + ko];
      #pragma unroll
      for (int im = 0; im < 4; im++)
        #pragma unroll
        for (int in = 0; in < 4; in++)
          acc[im][in] = __builtin_amdgcn_mfma_f32_16x16x32_bf16(
              af[im], bfr[in], acc[im][in], 0, 0, 0);
    }
    __syncthreads();
  }

  #pragma unroll
  for (int im = 0; im < 4; im++) {
    #pragma unroll
    for (int r = 0; r < 4; r++) {
      float rowsum = 0.f;
      #pragma unroll
      for (int in = 0; in < 4; in++) {
        int a_g = ntile * 128 + wn * 64 + in * 16 + l15;
        rowsum += fast_tanh(acc[im][in][r] + pb[a_g]) * ctx[a_g];
      }
      #pragma unroll
      for (int m = 1; m < 16; m <<= 1)
        rowsum += __shfl_xor(rowsum, m, 64);
      if (l15 == 0) {
        int rowg = mtile * 128 + wm * 64 + im * 16 + g * 4 + r;
        sp[(size_t)(ntile * 2 + wn) * MROWS + rowg] = rowsum;
      }
    }
  }
}

__global__ __launch_bounds__(256) void softmax8_kernel(
    const float* __restrict__ sp, const void* __restrict__ lens,
    float* __restrict__ wts)
{
  int b = blockIdx.x;
  int tid = threadIdx.x;
  int len = read_len(lens, b);
  float sc[8];
  #pragma unroll
  for (int i = 0; i < 8; i++) {
    int s = tid + i * 256;
    size_t row = (size_t)b * SS + s;
    float v = 0.f;
    #pragma unroll
    for (int p = 0; p < 8; p++) v += sp[(size_t)p * MROWS + row];
    sc[i] = v;
  }
  float m = -1e30f;
  #pragma unroll
  for (int i = 0; i < 8; i++)
    if (tid + i * 256 < len) m = fmaxf(m, sc[i]);
  #pragma unroll
  for (int off = 1; off < 64; off <<= 1) m = fmaxf(m, __shfl_xor(m, off, 64));
  __shared__ float redm[4];
  __shared__ float reds[4];
  int w = tid >> 6, lane = tid & 63;
  if (lane == 0) redm[w] = m;
  __syncthreads();
  m = fmaxf(fmaxf(redm[0], redm[1]), fmaxf(redm[2], redm[3]));
  float e[8]; float sum = 0.f;
  #pragma unroll
  for (int i = 0; i < 8; i++) {
    int s = tid + i * 256;
    e[i] = (s < len) ? __expf(sc[i] - m) : 0.f;
    sum += e[i];
  }
  #pragma unroll
  for (int off = 1; off < 64; off <<= 1) sum += __shfl_xor(sum, off, 64);
  if (lane == 0) reds[w] = sum;
  __syncthreads();
  sum = reds[0] + reds[1] + reds[2] + reds[3];
  float inv = 1.f / sum;
  #pragma unroll
  for (int i = 0; i < 8; i++) {
    int s = tid + i * 256;
    wts[(size_t)b * SS + s] = e[i] * inv;
  }
}

__global__ __launch_bounds__(256) void wsum_fb(
    const float* __restrict__ X, const float* __restrict__ wts,
    const void* __restrict__ lens, float* __restrict__ op)
{
  int sc = blockIdx.x;
  int b  = blockIdx.y;
  int tid = threadIdx.x;
  int s0 = sc * 128;
  int len = read_len(lens, b);
  int cnt = min(128, len - s0);
  float* o = op + ((size_t)sc * BB + b) * HH;
  if (cnt <= 0) {
    *(float2*)(o + tid * 2) = make_float2(0.f, 0.f);
    return;
  }
  __shared__ float wsh[128];
  __shared__ f32x4 red[128];
  if (tid < 128) wsh[tid] = wts[(size_t)b * SS + s0 + tid];
  __syncthreads();
  int h = (tid & 127) * 4;
  int sr = tid >> 7;
  f32x4 acc = (f32x4)0.f;
  for (int i = sr; i < cnt; i += 2) {
    float wv = wsh[i];
    const float* xr = X + ((size_t)b * SS + s0 + i) * HH + h;
    float4 xv = *(const float4*)xr;
    acc[0] += wv * xv.x;
    acc[1] += wv * xv.y;
    acc[2] += wv * xv.z;
    acc[3] += wv * xv.w;
  }
  if (sr == 1) red[tid & 127] = acc;
  __syncthreads();
  if (sr == 0) {
    f32x4 r2 = red[tid];
    acc[0] += r2[0]; acc[1] += r2[1]; acc[2] += r2[2]; acc[3] += r2[3];
    *(f32x4*)(o + h) = acc;
  }
}

__global__ __launch_bounds__(512) void reduce_kernel(
    const float* __restrict__ op, float* __restrict__ out)
{
  int b = blockIdx.x;
  int h = threadIdx.x;
  float v = 0.f;
  #pragma unroll
  for (int sc = 0; sc < 16; sc++) v += op[((size_t)sc * BB + b) * HH + h];
  out[(size_t)b * HH + h] = v;
}

extern "C" void kernel_launch(void* const* d_in, const int* in_sizes, int n_in,
                              void* d_out, int out_size, void* d_ws, size_t ws_size,
                              hipStream_t stream) {
  const float* X   = (const float*)d_in[0];
  const void*  lens = d_in[1];
  const float* ctx = (const float*)d_in[2];
  const float* W   = (const float*)d_in[3];
  const float* pb  = (const float*)d_in[4];
  float* out = (float*)d_out;

  char* ws = (char*)d_ws;
  const size_t WB_BYTES = (size_t)HH * HH * 2;             // 512 KB
  const size_t P_BYTES  = 1024ull * HH * 4;                // 2 MB
  const size_t PM_BYTES = 1024 * 4;                        // 4 KB
  const size_t NEED = WB_BYTES + P_BYTES + 2 * PM_BYTES;

  if (ws_size >= NEED) {
    unsigned short* Wb = (unsigned short*)ws;
    float* P  = (float*)(ws + WB_BYTES);
    float* pm = (float*)(ws + WB_BYTES + P_BYTES);
    float* ps = (float*)(ws + WB_BYTES + P_BYTES + PM_BYTES);

    convw_kernel<<<8, 256, 0, stream>>>(W, Wb);
    scores_fused<<<1024, 512, 0, stream>>>(X, Wb, lens, ctx, pb, P, pm, ps);
    combine_kernel<<<BB, 512, 0, stream>>>(P, pm, ps, lens, out);
  } else {
    const size_t SP_BYTES = 8ull * MROWS * 4;
    const size_t WT_BYTES = (size_t)BB * SS * 4;
    float* sp  = (float*)ws;
    float* wts = (float*)(ws + SP_BYTES);
    float* op  = (float*)(ws + SP_BYTES + WT_BYTES);

    scores_fb<<<4096, 256, 0, stream>>>(X, lens, ctx, W, pb, sp);
    softmax8_kernel<<<BB, 256, 0, stream>>>(sp, lens, wts);
    wsum_fb<<<dim3(16, BB), 256, 0, stream>>>(X, wts, lens, op);
    reduce_kernel<<<BB, 512, 0, stream>>>(op, out);
  }
}